// Round 9
// baseline (700.498 us; speedup 1.0000x reference)
//
#include <hip/hip_runtime.h>
#include <hip/hip_fp16.h>

typedef _Float16 f16;
typedef f16 f16x8 __attribute__((ext_vector_type(8)));
typedef f16 f16x2 __attribute__((ext_vector_type(2)));
typedef float f32x4 __attribute__((ext_vector_type(4)));

// Packed split-f16 weight images: 4 mats (W1a,W2a,W1b,W2b) x 2 planes (hi,lo),
// 65536 f16 per plane = 1 MiB. Layout + content VERIFIED (R6/R8 pass).
// f16-unit strides: mat 131072, plane 65536, frag 512, lane 8.
__device__ __align__(16) f16 g_wimg[524288];

// Per-group f32 scratch: 16 rows x 132 floats (128 + 4 pad) = 528 B/row.
// Pad rotates banks by 4/row (2-way worst case on transposes; no XOR).
#define RSTRIDE 528
#define GSTRIDE 8448  // 16 * RSTRIDE

// gelu(x) = 0.5 x (1 + erf(x/sqrt2)); erf via Abramowitz-Stegun 7.1.26 (|err|<1.5e-7)
__device__ __forceinline__ float gelu_f(float x) {
  float z = fabsf(x) * 0.70710678118654752f;
  float t = __builtin_amdgcn_rcpf(fmaf(0.3275911f, z, 1.0f));
  float p = fmaf(1.061405429f, t, -1.453152027f);
  p = fmaf(p, t, 1.421413741f);
  p = fmaf(p, t, -0.284496736f);
  p = fmaf(p, t, 0.254829592f);
  p = p * t;
  float e = __expf(-z * z);
  float er = fmaf(-p, e, 1.0f);
  er = copysignf(er, x);
  return 0.5f * x * (1.0f + er);
}

// ---------------------------------------------------------------------------
// prep_weights: byte-identical to the R6/R8 PASSING kernels (HW-verified).
//   frag = ((chunk*8 + cb)*4 + ks); byte = frag*1024 + lane*16 + j*2
//   element (lane, j) = B[k = ks*32 + (lane>>4)*8 + j][col = cb*16 + (lane&15)]
//   type1 (W1*): col_global = chunk*128 + col   (512-dim chunked)
//   type2 (W2*): k_global  = chunk*128 + k      (512-dim chunked)
// The B-frag image of W1 is identically the A-frag image of W1^T.
// ---------------------------------------------------------------------------
__global__ __launch_bounds__(256) void prep_weights(
    const float* __restrict__ W1a, const float* __restrict__ W2a,
    const float* __restrict__ W1b, const float* __restrict__ W2b) {
  int p = blockIdx.x * 256 + threadIdx.x;  // pair index, 262144 total
  int mat = p >> 16;
  int rem = p & 65535;
  int plane = rem >> 15;
  int rem2 = rem & 32767;
  int frag = rem2 >> 8;
  int q = rem2 & 255;
  int lane = q >> 2;
  int j = (q & 3) * 2;
  int chunk = frag >> 5;
  int cb = (frag >> 2) & 7;
  int ks = frag & 3;
  int l15 = lane & 15, l4 = lane >> 4;
  int col16 = cb * 16 + l15;
  int kk = ks * 32 + l4 * 8 + j;
  const float* W = (mat == 0) ? W1a : (mat == 1) ? W2a : (mat == 2) ? W1b : W2b;
  float s0, s1;
  if ((mat & 1) == 0) {
    int colg = chunk * 128 + col16;
    s0 = W[kk * 512 + colg];
    s1 = W[(kk + 1) * 512 + colg];
  } else {
    int kg = chunk * 128 + kk;
    s0 = W[kg * 128 + col16];
    s1 = W[(kg + 1) * 128 + col16];
  }
  f16x2 h;
  if (plane == 0) {
    h.x = (f16)s0;
    h.y = (f16)s1;
  } else {
    h.x = (f16)(s0 - (float)(f16)s0);
    h.y = (f16)(s1 - (float)(f16)s1);
  }
  *(f16x2*)((unsigned char*)g_wimg + mat * 262144 + plane * 131072 +
            frag * 1024 + lane * 16 + j * 2) = h;
}

// Split 8 f32 into hi/lo f16x8 fragments (error-free to 2^-24).
__device__ __forceinline__ void split8(const float4& a, const float4& b,
                                       f16x8& h, f16x8& l) {
  float v[8] = {a.x, a.y, a.z, a.w, b.x, b.y, b.z, b.w};
#pragma unroll
  for (int j = 0; j < 8; ++j) {
    f16 x = (f16)v[j];
    h[j] = x;
    l[j] = (f16)(v[j] - (float)x);
  }
}

// One MLP stage over TWO 16-row groups, fully wave-local, barrier-free.
// scr = this wave's private scratch (2 groups x [16][132] f32).
// bfh/bfl[g]: activation frags (B-operand, x^T) in regs for the whole stage.
// zacc[g][n]: C/D accumulator (row = l4*4+r, col = n*16+l15), enters = residual.
// 3-term split: hi*hi + lo*hi + hi*lo (dropped lo*lo ~ 2^-24 relative).
// Each weight-fragment load pair now feeds 6 MFMAs (2 groups) - 2x intensity.
__device__ __forceinline__ void mlp_stage(
    char* scr, const f16x8 (&bfh)[2][4], const f16x8 (&bfl)[2][4],
    f32x4 (&zacc)[2][8],
    const f16* __restrict__ W1img, const f16* __restrict__ W2img,
    const float* __restrict__ b1, int lane, int l15, int l4) {
  for (int chunk = 0; chunk < 4; ++chunk) {
    // ---- GEMM1 (swapped): t^T = W1^T-tile (A) x act^T (B), both groups ----
#pragma unroll
    for (int m = 0; m < 8; ++m) {
      f32x4 t4[2];
      t4[0] = (f32x4){0.f, 0.f, 0.f, 0.f};
      t4[1] = (f32x4){0.f, 0.f, 0.f, 0.f};
#pragma unroll
      for (int ks = 0; ks < 4; ++ks) {
        int frag = (chunk * 8 + m) * 4 + ks;
        f16x8 wh = *(const f16x8*)(W1img + frag * 512 + lane * 8);
        f16x8 wl = *(const f16x8*)(W1img + 65536 + frag * 512 + lane * 8);
#pragma unroll
        for (int g = 0; g < 2; ++g) {
          t4[g] = __builtin_amdgcn_mfma_f32_16x16x32_f16(wh, bfh[g][ks], t4[g], 0, 0, 0);
          t4[g] = __builtin_amdgcn_mfma_f32_16x16x32_f16(wl, bfh[g][ks], t4[g], 0, 0, 0);
          t4[g] = __builtin_amdgcn_mfma_f32_16x16x32_f16(wh, bfl[g][ks], t4[g], 0, 0, 0);
        }
      }
      // t4[g][r] = h_pre[group g][row=l15][col = chunk*128 + m*16 + l4*4 + r]
      float4 bv = *(const float4*)(b1 + chunk * 128 + m * 16 + l4 * 4);
#pragma unroll
      for (int g = 0; g < 2; ++g) {
        float4 gg;
        gg.x = gelu_f(t4[g][0] + bv.x);
        gg.y = gelu_f(t4[g][1] + bv.y);
        gg.z = gelu_f(t4[g][2] + bv.z);
        gg.w = gelu_f(t4[g][3] + bv.w);
        // wave-local transpose staging: h row l15, within-chunk col m*16+l4*4
        *(float4*)(scr + g * GSTRIDE + l15 * RSTRIDE + m * 64 + l4 * 16) = gg;
      }
    }
    // ---- GEMM2: zacc[g][n] += h[g][16][128] @ W2[chunk] ----
#pragma unroll
    for (int ks = 0; ks < 4; ++ks) {
      f16x8 ah[2], al[2];
#pragma unroll
      for (int g = 0; g < 2; ++g) {
        const char* hb = scr + g * GSTRIDE + l15 * RSTRIDE + ks * 128 + l4 * 32;
        float4 h0 = *(const float4*)(hb);
        float4 h1 = *(const float4*)(hb + 16);
        split8(h0, h1, ah[g], al[g]);
      }
#pragma unroll
      for (int n = 0; n < 8; ++n) {
        int frag = (chunk * 8 + n) * 4 + ks;
        f16x8 bh = *(const f16x8*)(W2img + frag * 512 + lane * 8);
        f16x8 bl = *(const f16x8*)(W2img + 65536 + frag * 512 + lane * 8);
#pragma unroll
        for (int g = 0; g < 2; ++g) {
          zacc[g][n] = __builtin_amdgcn_mfma_f32_16x16x32_f16(ah[g], bh, zacc[g][n], 0, 0, 0);
          zacc[g][n] = __builtin_amdgcn_mfma_f32_16x16x32_f16(al[g], bh, zacc[g][n], 0, 0, 0);
          zacc[g][n] = __builtin_amdgcn_mfma_f32_16x16x32_f16(ah[g], bl, zacc[g][n], 0, 0, 0);
        }
      }
    }
  }
}

// In-register LN over one group's 16 rows (C/D layout). Row stats via 16-lane
// (same-l4) shuffle reduce; no LDS, no barrier.
#define ROW_LN_STATS(ZACC, MMV, RSV)                                   \
  float MMV[4], RSV[4];                                                \
  _Pragma("unroll") for (int r = 0; r < 4; ++r) {                      \
    float s = 0.f, q = 0.f;                                            \
    _Pragma("unroll") for (int n = 0; n < 8; ++n) {                    \
      float v = ZACC[n][r];                                            \
      s += v;                                                          \
      q += v * v;                                                      \
    }                                                                  \
    _Pragma("unroll") for (int m = 8; m >= 1; m >>= 1) {               \
      s += __shfl_xor(s, m, 64);                                       \
      q += __shfl_xor(q, m, 64);                                       \
    }                                                                  \
    float mm = s * (1.f / 128.f);                                      \
    float var = q * (1.f / 128.f) - mm * mm;                           \
    MMV[r] = mm;                                                       \
    RSV[r] = rsqrtf(var + 1e-5f);                                      \
  }

__global__ __launch_bounds__(128, 2) void tsal_kernel(
    const float* __restrict__ x,
    const float* __restrict__ bo_time, const float* __restrict__ bo_recv,
    const float* __restrict__ g1, const float* __restrict__ be1,
    const float* __restrict__ g2, const float* __restrict__ be2,
    const float* __restrict__ g3, const float* __restrict__ be3,
    const float* __restrict__ g4, const float* __restrict__ be4,
    const float* __restrict__ b1a, const float* __restrict__ b2a,
    const float* __restrict__ b1b, const float* __restrict__ b2b,
    float* __restrict__ out) {
  __shared__ __align__(16) char smem[33792];  // 2 waves x 2 groups x 8448 B

  const int tid = threadIdx.x;
  const int lane = tid & 63;
  const int wv = tid >> 6;               // 0..1
  const int l15 = lane & 15, l4 = lane >> 4;
  char* scr = smem + wv * (2 * GSTRIDE);
  const int R0 = blockIdx.x * 64 + wv * 32;  // this wave's 32 rows

  // ---------------- Phase 0: LN1(x + bo_time) -> f32 scratch ----------------
  // 2 rows/iter: lanes 0-31 row rl, lanes 32-63 row rl+1. Wave-local.
#pragma unroll
  for (int it = 0; it < 16; ++it) {
    int rl = it * 2 + (lane >> 5);       // 0..31
    int c0 = (lane & 31) * 4;
    float4 xv = *(const float4*)(x + (size_t)(R0 + rl) * 128 + c0);
    float4 bt = *(const float4*)(bo_time + c0);
    float vx = xv.x + bt.x, vy = xv.y + bt.y, vz = xv.z + bt.z, vw = xv.w + bt.w;
    float s = vx + vy + vz + vw;
    float q = vx * vx + vy * vy + vz * vz + vw * vw;
#pragma unroll
    for (int m = 16; m >= 1; m >>= 1) {
      s += __shfl_xor(s, m, 64);
      q += __shfl_xor(q, m, 64);
    }
    float mm = s * (1.f / 128.f);
    float rs = rsqrtf(q * (1.f / 128.f) - mm * mm + 1e-5f);
    float4 gv = *(const float4*)(g1 + c0);
    float4 bv = *(const float4*)(be1 + c0);
    float4 w;
    w.x = (vx - mm) * rs * gv.x + bv.x;
    w.y = (vy - mm) * rs * gv.y + bv.y;
    w.z = (vz - mm) * rs * gv.z + bv.z;
    w.w = (vw - mm) * rs * gv.w + bv.w;
    *(float4*)(scr + (rl >> 4) * GSTRIDE + (rl & 15) * RSTRIDE + c0 * 4) = w;
  }

  // ---- activation B-frags of w^T (held in regs all of stage A) ----
  // bfh[g][ks] elem j = w[g][l15][ks*32 + l4*8 + j]
  f16x8 bfh[2][4], bfl[2][4];
#pragma unroll
  for (int g = 0; g < 2; ++g)
#pragma unroll
    for (int ks = 0; ks < 4; ++ks) {
      const char* wb = scr + g * GSTRIDE + l15 * RSTRIDE + ks * 128 + l4 * 32;
      float4 a0 = *(const float4*)(wb);
      float4 a1 = *(const float4*)(wb + 16);
      split8(a0, a1, bfh[g][ks], bfl[g][ks]);
    }
  // ---- residual w into zacc (C/D layout scalar reads, exact f32) ----
  f32x4 zacc[2][8];
#pragma unroll
  for (int g = 0; g < 2; ++g)
#pragma unroll
    for (int n = 0; n < 8; ++n)
#pragma unroll
      for (int r = 0; r < 4; ++r)
        zacc[g][n][r] = *(const float*)(scr + g * GSTRIDE +
                                        (l4 * 4 + r) * RSTRIDE +
                                        (n * 16 + l15) * 4);

  // ---------------- Stage A: z_pre = w + MLP1(w) ----------------
  mlp_stage(scr, bfh, bfl, zacc, g_wimg, g_wimg + 131072, b1a, lane, l15, l4);

  // + b2a; LN2; + bo_recv; LN3 -> y (all in-register, per group)
  float b2v[8], g2v[8], be2v[8], brv[8], g3v[8], be3v[8];
#pragma unroll
  for (int n = 0; n < 8; ++n) {
    int col = n * 16 + l15;
    b2v[n] = b2a[col];
    g2v[n] = g2[col];
    be2v[n] = be2[col];
    brv[n] = bo_recv[col];
    g3v[n] = g3[col];
    be3v[n] = be3[col];
  }
#pragma unroll
  for (int g = 0; g < 2; ++g) {
#pragma unroll
    for (int n = 0; n < 8; ++n)
#pragma unroll
      for (int r = 0; r < 4; ++r) zacc[g][n][r] += b2v[n];
    {
      ROW_LN_STATS(zacc[g], mm2, rs2)
#pragma unroll
      for (int n = 0; n < 8; ++n)
#pragma unroll
        for (int r = 0; r < 4; ++r)
          zacc[g][n][r] =
              (zacc[g][n][r] - mm2[r]) * rs2[r] * g2v[n] + be2v[n] + brv[n];
    }
    {
      ROW_LN_STATS(zacc[g], mm3, rs3)
#pragma unroll
      for (int n = 0; n < 8; ++n)
#pragma unroll
        for (int r = 0; r < 4; ++r)
          zacc[g][n][r] = (zacc[g][n][r] - mm3[r]) * rs3[r] * g3v[n] + be3v[n];
    }
    // write y to scratch (C/D pattern), rebuild activation frags (y^T)
#pragma unroll
    for (int n = 0; n < 8; ++n)
#pragma unroll
      for (int r = 0; r < 4; ++r)
        *(float*)(scr + g * GSTRIDE + (l4 * 4 + r) * RSTRIDE +
                  (n * 16 + l15) * 4) = zacc[g][n][r];
#pragma unroll
    for (int ks = 0; ks < 4; ++ks) {
      const char* yb = scr + g * GSTRIDE + l15 * RSTRIDE + ks * 128 + l4 * 32;
      float4 a0 = *(const float4*)(yb);
      float4 a1 = *(const float4*)(yb + 16);
      split8(a0, a1, bfh[g][ks], bfl[g][ks]);
    }
  }

  // ---------------- Stage B: o_pre = y + MLP2(y) ----------------
  mlp_stage(scr, bfh, bfl, zacc, g_wimg + 262144, g_wimg + 393216, b1b, lane,
            l15, l4);

  // + b2b; LN4 -> out (per group)
  float b4v[8], g4v[8], be4v[8];
#pragma unroll
  for (int n = 0; n < 8; ++n) {
    int col = n * 16 + l15;
    b4v[n] = b2b[col];
    g4v[n] = g4[col];
    be4v[n] = be4[col];
  }
#pragma unroll
  for (int g = 0; g < 2; ++g) {
#pragma unroll
    for (int n = 0; n < 8; ++n)
#pragma unroll
      for (int r = 0; r < 4; ++r) zacc[g][n][r] += b4v[n];
    {
      ROW_LN_STATS(zacc[g], mm4, rs4)
#pragma unroll
      for (int n = 0; n < 8; ++n)
#pragma unroll
        for (int r = 0; r < 4; ++r) {
          float o = (zacc[g][n][r] - mm4[r]) * rs4[r] * g4v[n] + be4v[n];
          out[(size_t)(R0 + g * 16 + l4 * 4 + r) * 128 + n * 16 + l15] = o;
        }
    }
  }
}

extern "C" void kernel_launch(void* const* d_in, const int* in_sizes, int n_in,
                              void* d_out, int out_size, void* d_ws, size_t ws_size,
                              hipStream_t stream) {
  const float* x = (const float*)d_in[0];
  // d_in[1] = router (dead), d_in[3] = bo_send (dead)
  const float* bo_time = (const float*)d_in[2];
  const float* bo_recv = (const float*)d_in[4];
  const float* g1 = (const float*)d_in[5];
  const float* be1 = (const float*)d_in[6];
  const float* g2 = (const float*)d_in[7];
  const float* be2 = (const float*)d_in[8];
  const float* g3 = (const float*)d_in[9];
  const float* be3 = (const float*)d_in[10];
  const float* g4 = (const float*)d_in[11];
  const float* be4 = (const float*)d_in[12];
  const float* W1a = (const float*)d_in[13];
  const float* b1a = (const float*)d_in[14];
  const float* W2a = (const float*)d_in[15];
  const float* b2a = (const float*)d_in[16];
  const float* W1b = (const float*)d_in[17];
  const float* b1b = (const float*)d_in[18];
  const float* W2b = (const float*)d_in[19];
  const float* b2b = (const float*)d_in[20];
  float* outp = (float*)d_out;

  int nrows = in_sizes[0] / 128;  // 131072
  prep_weights<<<1024, 256, 0, stream>>>(W1a, W2a, W1b, W2b);
  tsal_kernel<<<nrows / 64, 128, 0, stream>>>(
      x, bo_time, bo_recv, g1, be1, g2, be2, g3, be3, g4, be4,
      b1a, b2a, b1b, b2b, outp);
}